// Round 1
// baseline (1039.040 us; speedup 1.0000x reference)
//
#include <hip/hip_runtime.h>
#include <cmath>

// Problem constants
#define NPTS   1000000
#define GXD    116
#define GYD    87
#define NB     4
#define NSEG   40368          // NB*GXD*GYD
#define OUTN   25690112       // 4*128*224*224

// workspace layout in 4-byte elements (total ~70.9 MB; requires ws_size >= ~71MB)
#define OFF_INV    0          // NPTS int
#define OFF_SORT   1000000    // NPTS int
#define OFF_CNT    2000000    // NSEG int
#define OFF_OFFS   2050000    // NSEG+1 int
#define OFF_FILL   2100000    // NSEG int
#define OFF_STATS  2150000    // float: [0..14) S-moments, [16..144) sum1, [144..272) ss1
#define OFF_BN0    2150400    // float: [0..32) a0, [32..64) b0'
#define OFF_MINP   2160000    // NSEG*128 float
#define OFF_MAXP   7350000    // NSEG*128 float
#define OFF_DENSE  12550000   // 4*128*87*116 float

__device__ __forceinline__ float swishf(float z) { return z / (1.0f + __expf(-z)); }
__device__ __forceinline__ float bcastf(float v, int l) {
  return __builtin_bit_cast(float, __builtin_amdgcn_readlane(__builtin_bit_cast(int, v), l));
}

__global__ __launch_bounds__(256) void k_init(int* __restrict__ cnt, int* __restrict__ fill,
                                              float* __restrict__ stats) {
  int i = blockIdx.x * 256 + threadIdx.x;
  if (i < NSEG) { cnt[i] = 0; fill[i] = 0; }
  if (i < 400) stats[i] = 0.0f;
}

// Pass 1: inv + cnt + feats moment matrix (S1[4], upper-tri S2[10])
__global__ __launch_bounds__(256) void k_point1(const float* __restrict__ pts,
                                                int* __restrict__ inv,
                                                int* __restrict__ cnt,
                                                float* __restrict__ Sg) {
  int i = blockIdx.x * 256 + threadIdx.x;
  float vals[14];
  #pragma unroll
  for (int q = 0; q < 14; ++q) vals[q] = 0.0f;
  if (i < NPTS) {
    float b = pts[i*5+0], x = pts[i*5+1], y = pts[i*5+2], t = pts[i*5+3], p = pts[i*5+4];
    int cx = (int)floorf(x / 3.0f);      // exact IEEE divide: matches jax floor(x/VX)
    int cy = (int)floorf(y / 3.0f);
    int bi = (int)b;
    if (cx >= 0 && cx < GXD && cy >= 0 && cy < GYD && bi >= 0 && bi < NB) {
      int iv = (bi*GXD + cx)*GYD + cy;
      inv[i] = iv;
      atomicAdd(&cnt[iv], 1);
    } else {
      inv[i] = -1;   // jax segment ops drop out-of-range ids
    }
    // BN0 is over ALL points (reference computes feats for every point)
    float f0 = x/346.0f, f1 = y/260.0f, f2 = t/200.0f, f3 = p;
    vals[0]=f0; vals[1]=f1; vals[2]=f2; vals[3]=f3;
    vals[4]=f0*f0; vals[5]=f0*f1; vals[6]=f0*f2; vals[7]=f0*f3;
    vals[8]=f1*f1; vals[9]=f1*f2; vals[10]=f1*f3;
    vals[11]=f2*f2; vals[12]=f2*f3; vals[13]=f3*f3;
  }
  __shared__ float lds[4*14];
  int lane = threadIdx.x & 63, wave = threadIdx.x >> 6;
  #pragma unroll
  for (int q = 0; q < 14; ++q) {
    float v = vals[q];
    #pragma unroll
    for (int d = 32; d > 0; d >>= 1) v += __shfl_down(v, d, 64);
    if (lane == 0) lds[wave*14 + q] = v;
  }
  __syncthreads();
  if (threadIdx.x < 14) {
    float v = lds[threadIdx.x] + lds[14+threadIdx.x] + lds[28+threadIdx.x] + lds[42+threadIdx.x];
    atomicAdd(&Sg[threadIdx.x], v);
  }
}

// BN0 coefficients (from moments) + exclusive scan of cnt -> offs (single block)
__global__ __launch_bounds__(1024) void k_scan(const int* __restrict__ cnt,
                                               int* __restrict__ offs,
                                               const float* __restrict__ S,
                                               float* __restrict__ bn0,
                                               const float* __restrict__ W0,
                                               const float* __restrict__ g0,
                                               const float* __restrict__ b0) {
  __shared__ int buf[1024];
  __shared__ int carry_s;
  const int tid = threadIdx.x;
  if (tid < 32) {
    const float invN = 1.0f / (float)NPTS;
    float w0 = W0[tid], w1 = W0[32+tid], w2 = W0[64+tid], w3 = W0[96+tid];
    float mu = (S[0]*w0 + S[1]*w1 + S[2]*w2 + S[3]*w3) * invN;
    float e2 = (S[4]*w0*w0 + S[8]*w1*w1 + S[11]*w2*w2 + S[13]*w3*w3
              + 2.0f*(S[5]*w0*w1 + S[6]*w0*w2 + S[7]*w0*w3
                    + S[9]*w1*w2 + S[10]*w1*w3 + S[12]*w2*w3)) * invN;
    float var = e2 - mu*mu;
    float a = rsqrtf(var + 1e-3f) * g0[tid];
    bn0[tid] = a;
    bn0[32+tid] = b0[tid] - mu*a;
  }
  if (tid == 0) carry_s = 0;
  __syncthreads();
  for (int base = 0; base < NSEG; base += 1024) {
    int i = base + tid;
    int v = (i < NSEG) ? cnt[i] : 0;
    buf[tid] = v;
    __syncthreads();
    for (int d = 1; d < 1024; d <<= 1) {
      int t = (tid >= d) ? buf[tid - d] : 0;
      __syncthreads();
      buf[tid] += t;
      __syncthreads();
    }
    int incl = buf[tid];
    if (i < NSEG) offs[i] = carry_s + incl - v;   // exclusive
    __syncthreads();
    if (tid == 1023) carry_s += incl;
    __syncthreads();
  }
  if (tid == 0) offs[NSEG] = carry_s;
}

// Counting-sort scatter: point ids grouped by segment
__global__ __launch_bounds__(256) void k_scatter(const int* __restrict__ inv,
                                                 const int* __restrict__ offs,
                                                 int* __restrict__ fill,
                                                 int* __restrict__ sortedIdx) {
  int i = blockIdx.x * 256 + threadIdx.x;
  if (i >= NPTS) return;
  int iv = inv[i];
  if (iv < 0) return;
  int pos = offs[iv] + atomicAdd(&fill[iv], 1);
  sortedIdx[pos] = i;
}

// Main segment pass: one wave per segment.
// Phase 1: m0[32] (segment max of h0) held in registers.
// Phase 2: pre1 = x1@W1 (x1=[h0,m0]); wave-local min/max per feature (swish-extreme
// trick makes that sufficient for segment_max(h1)), plus global sum/sumsq for BN1.
__global__ __launch_bounds__(256) void k_seg(const float* __restrict__ pts,
                                             const int* __restrict__ sortedIdx,
                                             const int* __restrict__ offs,
                                             const float* __restrict__ W0,
                                             const float* __restrict__ bn0,
                                             const float* __restrict__ W1g,
                                             float* __restrict__ minp,
                                             float* __restrict__ maxp,
                                             float* __restrict__ stats) {
  __shared__ __align__(16) float w1s[64*128];
  __shared__ float red[4][64][4];
  const int tid = threadIdx.x;
  for (int i = tid; i < 64*128; i += 256) w1s[i] = W1g[i];
  __syncthreads();
  const int wave = tid >> 6, lane = tid & 63, j = lane & 31;
  const float w0a = W0[j], w0b = W0[32+j], w0c = W0[64+j], w0d = W0[96+j];
  const float a0 = bn0[j], c0 = bn0[32+j];
  float sac0 = 0.f, sac1 = 0.f, ssc0 = 0.f, ssc1 = 0.f;
  const int nw = gridDim.x * 4;
  for (int s = blockIdx.x*4 + wave; s < NSEG; s += nw) {
    const int off = offs[s];
    const int n = offs[s+1] - off;
    if (n <= 0) continue;
    // ---- phase 1: m0 (half-waves take even/odd points, feature j = lane&31)
    float mx = -1e30f;
    const int half = lane >> 5;
    for (int p0 = off; p0 < off + n; p0 += 2) {
      int p = p0 + half;
      bool valid = (p < off + n);
      int idx = sortedIdx[valid ? p : off];
      float x = pts[idx*5+1], y = pts[idx*5+2], t = pts[idx*5+3], pw = pts[idx*5+4];
      float pre = (x/346.0f)*w0a + (y/260.0f)*w0b + (t/200.0f)*w0c + pw*w0d;
      float h = swishf(a0*pre + c0);
      if (valid) mx = fmaxf(mx, h);
    }
    const float m0 = fmaxf(mx, __shfl_xor(mx, 32, 64)); // every lane: m0 for feature lane&31
    // ---- phase 2: lane holds x1[lane]; computes features 2*lane, 2*lane+1; 4 points in flight
    float mn0 = 1e30f, mn1 = 1e30f, mh0 = -1e30f, mh1 = -1e30f;
    int p = off;
    const int pend = off + n;
    while (p < pend) {
      int np = pend - p; if (np > 4) np = 4;
      float vv[4];
      #pragma unroll
      for (int g = 0; g < 4; ++g) {
        int q = p + (g < np ? g : 0);
        int idx = __builtin_amdgcn_readfirstlane(sortedIdx[q]);  // wave-uniform -> scalar loads
        float x = pts[idx*5+1], y = pts[idx*5+2], t = pts[idx*5+3], pw = pts[idx*5+4];
        float pre = (x/346.0f)*w0a + (y/260.0f)*w0b + (t/200.0f)*w0c + pw*w0d;
        float h = swishf(a0*pre + c0);
        vv[g] = (lane < 32) ? h : m0;
      }
      float ac00=0.f, ac01=0.f, ac10=0.f, ac11=0.f, ac20=0.f, ac21=0.f, ac30=0.f, ac31=0.f;
      #pragma unroll 16
      for (int k = 0; k < 64; ++k) {
        const float2 w = *(const float2*)&w1s[k*128 + 2*lane];
        float x0 = bcastf(vv[0], k);
        float x1 = bcastf(vv[1], k);
        float x2 = bcastf(vv[2], k);
        float x3 = bcastf(vv[3], k);
        ac00 = fmaf(x0, w.x, ac00); ac01 = fmaf(x0, w.y, ac01);
        ac10 = fmaf(x1, w.x, ac10); ac11 = fmaf(x1, w.y, ac11);
        ac20 = fmaf(x2, w.x, ac20); ac21 = fmaf(x2, w.y, ac21);
        ac30 = fmaf(x3, w.x, ac30); ac31 = fmaf(x3, w.y, ac31);
      }
      float a0s[4] = {ac00, ac10, ac20, ac30};
      float a1s[4] = {ac01, ac11, ac21, ac31};
      #pragma unroll
      for (int g = 0; g < 4; ++g) {
        if (g < np) {
          mn0 = fminf(mn0, a0s[g]); mh0 = fmaxf(mh0, a0s[g]);
          mn1 = fminf(mn1, a1s[g]); mh1 = fmaxf(mh1, a1s[g]);
          sac0 += a0s[g]; ssc0 += a0s[g]*a0s[g];
          sac1 += a1s[g]; ssc1 += a1s[g]*a1s[g];
        }
      }
      p += np;
    }
    *(float2*)&minp[s*128 + 2*lane] = make_float2(mn0, mn1);
    *(float2*)&maxp[s*128 + 2*lane] = make_float2(mh0, mh1);
  }
  red[wave][lane][0] = sac0; red[wave][lane][1] = sac1;
  red[wave][lane][2] = ssc0; red[wave][lane][3] = ssc1;
  __syncthreads();
  if (wave == 0) {
    float t0 = red[0][lane][0] + red[1][lane][0] + red[2][lane][0] + red[3][lane][0];
    float t1 = red[0][lane][1] + red[1][lane][1] + red[2][lane][1] + red[3][lane][1];
    float t2 = red[0][lane][2] + red[1][lane][2] + red[2][lane][2] + red[3][lane][2];
    float t3 = red[0][lane][3] + red[1][lane][3] + red[2][lane][3] + red[3][lane][3];
    atomicAdd(&stats[16 + 2*lane],     t0);
    atomicAdd(&stats[16 + 2*lane + 1], t1);
    atomicAdd(&stats[144 + 2*lane],     t2);
    atomicAdd(&stats[144 + 2*lane + 1], t3);
  }
}

// Dense grid: BN1 + swish at pre-extremes (exact segment_max via quasiconvexity),
// with LDS transpose so both minp reads and dense writes are coalesced.
__global__ __launch_bounds__(256) void k_dense(const float* __restrict__ minp,
                                               const float* __restrict__ maxp,
                                               const int* __restrict__ offs,
                                               const float* __restrict__ stats,
                                               const float* __restrict__ g1,
                                               const float* __restrict__ b1,
                                               float* __restrict__ dense) {
  __shared__ float tile[116*129];  // +1 pad breaks bank conflicts on transposed read
  const int b = blockIdx.x / GYD;
  const int gy = blockIdx.x % GYD;
  const int tid = threadIdx.x;
  const float invN = 1.0f / (float)NPTS;
  for (int i = tid; i < 116*128; i += 256) {
    int gx = i >> 7, c = i & 127;
    int s = (b*GXD + gx)*GYD + gy;
    float m = 0.0f;
    if (offs[s+1] - offs[s] > 0) {
      float mu = stats[16+c] * invN;
      float var = stats[144+c] * invN - mu*mu;
      float a = rsqrtf(var + 1e-3f) * g1[c];
      float bb = b1[c] - mu*a;
      float zl = a*minp[s*128+c] + bb;
      float zh = a*maxp[s*128+c] + bb;
      m = fmaxf(swishf(zl), swishf(zh));
    }
    tile[gx*129 + c] = m;
  }
  __syncthreads();
  for (int i = tid; i < 128*116; i += 256) {
    int c = i / 116, gx = i % 116;
    dense[((b*128 + c)*GYD + gy)*GXD + gx] = tile[gx*129 + c];
  }
}

// Bilinear resize (align-corners), dense (4,128,87,116) -> out (4,128,224,224)
__global__ __launch_bounds__(256) void k_resize(const float* __restrict__ dense,
                                                float* __restrict__ out) {
  int o = blockIdx.x * 256 + threadIdx.x;
  if (o >= OUTN) return;
  int xo = o % 224;
  int r = o / 224;
  int yo = r % 224;
  int bc = r / 224;
  float ys = (float)yo * (86.0f/223.0f);
  float xs = (float)xo * (115.0f/223.0f);
  float yf = floorf(ys); int y0 = (int)yf; int y1 = min(y0+1, 86); float wy = ys - yf;
  float xf = floorf(xs); int x0 = (int)xf; int x1 = min(x0+1, 115); float wx = xs - xf;
  const float* d = dense + bc*(87*116);
  float d00 = d[y0*116+x0], d01 = d[y0*116+x1];
  float d10 = d[y1*116+x0], d11 = d[y1*116+x1];
  float c0v = d00*(1.0f-wy) + d10*wy;
  float c1v = d01*(1.0f-wy) + d11*wy;
  out[o] = c0v*(1.0f-wx) + c1v*wx;
}

extern "C" void kernel_launch(void* const* d_in, const int* in_sizes, int n_in,
                              void* d_out, int out_size, void* d_ws, size_t ws_size,
                              hipStream_t stream) {
  // setup_inputs order: fus(unused), points, W0, g0, b0, W1, g1, b1
  const float* pts = (const float*)d_in[1];
  const float* W0  = (const float*)d_in[2];
  const float* g0  = (const float*)d_in[3];
  const float* b0  = (const float*)d_in[4];
  const float* W1  = (const float*)d_in[5];
  const float* g1  = (const float*)d_in[6];
  const float* b1  = (const float*)d_in[7];
  float* out = (float*)d_out;
  int*   wsi = (int*)d_ws;
  float* wsf = (float*)d_ws;

  k_init<<<158, 256, 0, stream>>>(wsi+OFF_CNT, wsi+OFF_FILL, wsf+OFF_STATS);
  k_point1<<<(NPTS+255)/256, 256, 0, stream>>>(pts, wsi+OFF_INV, wsi+OFF_CNT, wsf+OFF_STATS);
  k_scan<<<1, 1024, 0, stream>>>(wsi+OFF_CNT, wsi+OFF_OFFS, wsf+OFF_STATS, wsf+OFF_BN0, W0, g0, b0);
  k_scatter<<<(NPTS+255)/256, 256, 0, stream>>>(wsi+OFF_INV, wsi+OFF_OFFS, wsi+OFF_FILL, wsi+OFF_SORT);
  k_seg<<<2048, 256, 0, stream>>>(pts, wsi+OFF_SORT, wsi+OFF_OFFS, W0, wsf+OFF_BN0, W1,
                                  wsf+OFF_MINP, wsf+OFF_MAXP, wsf+OFF_STATS);
  k_dense<<<NB*GYD, 256, 0, stream>>>(wsf+OFF_MINP, wsf+OFF_MAXP, wsi+OFF_OFFS, wsf+OFF_STATS,
                                      g1, b1, wsf+OFF_DENSE);
  k_resize<<<(OUTN+255)/256, 256, 0, stream>>>(wsf+OFF_DENSE, out);
}